// Round 10
// baseline (129.703 us; speedup 1.0000x reference)
//
#include <hip/hip_runtime.h>
#include <hip/hip_bf16.h>
#include <hip/hip_fp16.h>
#include <math.h>

// Output layout (float32, concatenated in reference return order):
//   rendered [128,1,28,28]  @ 0       (100352)
//   mu       [128,64]       @ 100352  (8192)
//   logvar   [128,64]       @ 108544  (8192)
//   cp       [128,2,3,4,2]  @ 116736  (6144)
//   widths   [128,2]        @ 122880  (256)
//   alphas   [128,2]        @ 123136  (256)
#define REND_OFF 0
#define MU_OFF   100352
#define LV_OFF   108544
#define CP_OFF   116736
#define W_OFF    122880
#define A_OFF    123136

// fp16 weight workspace, k-pair COLUMN packed for v_dot2_f32_f16 (r6 layout):
// uint4 q at (k2, j4): q.x = {W[2k2][4j4], W[2k2+1][4j4]} as half2, q.y..q.w
// the next 3 columns. Layer uint4 bases:
#define Q_W1 0       // [400][64]  (K padded 784->800)
#define Q_W2 25600   // [128][64]
#define Q_ML 33792   // [128][32]  (mu|lv fused, N=128)
#define Q_D1 37888   // [32][128]
#define Q_D2 41984   // [256][128]
#define Q_H  74752   // [256][16]  (p|wd|a|pad0, N=64)
#define Q_TOT 78848

typedef _Float16 half2_t __attribute__((ext_vector_type(2)));

__device__ __forceinline__ float leakyf(float x) {
    return x >= 0.f ? x : 0.2f * x;
}
__device__ __forceinline__ float seluf(float x) {
    const float sc = 1.0507009873554805f;
    const float al = 1.6732632423543772f;
    return x > 0.f ? sc * x : sc * al * expm1f(x);
}
__device__ __forceinline__ float sigmoidf(float x) {
    return 1.f / (1.f + expf(-x));
}
__device__ __forceinline__ unsigned pkh(float a, float b) {
    __half ha = __float2half(a), hb = __float2half(b);
    return (unsigned)__half_as_ushort(ha) | ((unsigned)__half_as_ushort(hb) << 16);
}
__device__ __forceinline__ half2_t as_h2(unsigned u) {
    union { unsigned u; half2_t h; } c; c.u = u; return c.h;
}
__device__ __forceinline__ float dot2(unsigned a, unsigned w, float acc) {
#if __has_builtin(__builtin_amdgcn_fdot2)
    return __builtin_amdgcn_fdot2(as_h2(a), as_h2(w), acc, false);
#else
    half2_t ah = as_h2(a), wh = as_h2(w);
    acc = fmaf((float)ah[0], (float)wh[0], acc);
    return fmaf((float)ah[1], (float)wh[1], acc);
#endif
}

// ---- kernel 0: build k-pair column-packed fp16 weight workspace (== r6) ----
__global__ __launch_bounds__(256) void conv_w(
    const float* __restrict__ e_w1, const float* __restrict__ e_w2,
    const float* __restrict__ w_mu, const float* __restrict__ w_lv,
    const float* __restrict__ d_w1, const float* __restrict__ d_w2,
    const float* __restrict__ p_w,  const float* __restrict__ wd_w,
    const float* __restrict__ a_w,  uint4* __restrict__ wsq)
{
    int t = blockIdx.x * 256 + threadIdx.x;
    if (t >= Q_TOT) return;
    float lo[4], hi[4];
    if (t < Q_W2) {                       // W1: [800pad][256]
        int q = t, k2 = q >> 6, j4 = q & 63;
        int k0 = 2 * k2, c0 = 4 * j4;
        #pragma unroll
        for (int c = 0; c < 4; ++c) {
            lo[c] = (k0     < 784) ? e_w1[k0 * 256 + c0 + c] : 0.f;
            hi[c] = (k0 + 1 < 784) ? e_w1[(k0 + 1) * 256 + c0 + c] : 0.f;
        }
    } else if (t < Q_ML) {                // W2: [256][256]
        int q = t - Q_W2, k2 = q >> 6, j4 = q & 63;
        int k0 = 2 * k2, c0 = 4 * j4;
        #pragma unroll
        for (int c = 0; c < 4; ++c) {
            lo[c] = e_w2[k0 * 256 + c0 + c];
            hi[c] = e_w2[(k0 + 1) * 256 + c0 + c];
        }
    } else if (t < Q_D1) {                // ML: [256][128] = mu|lv
        int q = t - Q_ML, k2 = q >> 5, j4 = q & 31;
        int k0 = 2 * k2, c0 = 4 * j4;
        #pragma unroll
        for (int c = 0; c < 4; ++c) {
            int cc = c0 + c;
            lo[c] = (cc < 64) ? w_mu[k0 * 64 + cc] : w_lv[k0 * 64 + cc - 64];
            hi[c] = (cc < 64) ? w_mu[(k0 + 1) * 64 + cc]
                              : w_lv[(k0 + 1) * 64 + cc - 64];
        }
    } else if (t < Q_D2) {                // D1: [64][512]
        int q = t - Q_D1, k2 = q >> 7, j4 = q & 127;
        int k0 = 2 * k2, c0 = 4 * j4;
        #pragma unroll
        for (int c = 0; c < 4; ++c) {
            lo[c] = d_w1[k0 * 512 + c0 + c];
            hi[c] = d_w1[(k0 + 1) * 512 + c0 + c];
        }
    } else if (t < Q_H) {                 // D2: [512][512]
        int q = t - Q_D2, k2 = q >> 7, j4 = q & 127;
        int k0 = 2 * k2, c0 = 4 * j4;
        #pragma unroll
        for (int c = 0; c < 4; ++c) {
            lo[c] = d_w2[k0 * 512 + c0 + c];
            hi[c] = d_w2[(k0 + 1) * 512 + c0 + c];
        }
    } else {                              // H: [512][64] = p|wd|a|0
        int q = t - Q_H, k2 = q >> 4, j4 = q & 15;
        int k0 = 2 * k2, c0 = 4 * j4;
        #pragma unroll
        for (int c = 0; c < 4; ++c) {
            int cc = c0 + c;
            lo[c] = (cc < 40) ? p_w[k0 * 40 + cc]
                  : (cc < 42) ? wd_w[k0 * 2 + cc - 40]
                  : (cc < 44) ? a_w[k0 * 2 + cc - 42] : 0.f;
            hi[c] = (cc < 40) ? p_w[(k0 + 1) * 40 + cc]
                  : (cc < 42) ? wd_w[(k0 + 1) * 2 + cc - 40]
                  : (cc < 44) ? a_w[(k0 + 1) * 2 + cc - 42] : 0.f;
        }
    }
    uint4 u;
    u.x = pkh(lo[0], hi[0]);
    u.y = pkh(lo[1], hi[1]);
    u.z = pkh(lo[2], hi[2]);
    u.w = pkh(lo[3], hi[3]);
    wsq[t] = u;
}

// ---- layer slice GEMM via v_dot2_f32_f16 (== r6: coalesced wave loads) ----
// N cols, JG = N/4 col groups, S = 1024/JG k-slices, Ks k-pairs per thread.
template<int N, int JG, int S, int Ks>
__device__ __forceinline__ void hgemm(const uint4* __restrict__ wq,
                                      const unsigned* __restrict__ xu,
                                      float* __restrict__ red, int tid)
{
    constexpr int NTp = N + 4;
    const int jg = tid % JG, ks = tid / JG;
    const uint4* wp = wq + (ks * Ks) * (N / 4) + jg;
    const unsigned* xp = xu + ks * Ks;
    float a0 = 0.f, a1 = 0.f, a2 = 0.f, a3 = 0.f;
    #pragma unroll 8
    for (int kk = 0; kk < Ks; ++kk) {
        uint4 w = wp[kk * (N / 4)];
        unsigned av = xp[kk];
        a0 = dot2(av, w.x, a0);
        a1 = dot2(av, w.y, a1);
        a2 = dot2(av, w.z, a2);
        a3 = dot2(av, w.w, a3);
    }
    *(float4*)&red[ks * NTp + 4 * jg] = make_float4(a0, a1, a2, a3);
}

// reduce S slices, apply act, pack adjacent unit pairs to half2 (== r6)
template<int N, int S, int ACT>
__device__ __forceinline__ void reduce_pack(const float* __restrict__ red,
                                            const float* __restrict__ bias,
                                            unsigned* __restrict__ Cu, int tid)
{
    constexpr int NTp = N + 4;
    if (tid < N / 2) {
        int j0 = 2 * tid;
        float s0 = bias[j0], s1 = bias[j0 + 1];
        #pragma unroll
        for (int si = 0; si < S; ++si) {
            s0 += red[si * NTp + j0];
            s1 += red[si * NTp + j0 + 1];
        }
        if (ACT == 1) { s0 = leakyf(s0); s1 = leakyf(s1); }
        else          { s0 = seluf(s0);  s1 = seluf(s1);  }
        Cu[tid] = pkh(s0, s1);
    }
}

// ---- fused MLP + RENDER: 128 blocks x 1024 thr; 1 batch elem per block ----
__global__ __launch_bounds__(1024) void vae_mlp(
    const float* __restrict__ x,    const float* __restrict__ eps,
    const float* __restrict__ e_b1, const float* __restrict__ e_b2,
    const float* __restrict__ b_mu, const float* __restrict__ b_lv,
    const float* __restrict__ d_b1, const float* __restrict__ d_b2,
    const float* __restrict__ p_b,  const float* __restrict__ wd_b,
    const float* __restrict__ a_b,
    const uint4* __restrict__ wsq,  float* __restrict__ out)
{
    const int b   = blockIdx.x;
    const int tid = threadIdx.x;

    __shared__ __align__(16) unsigned xs[400];    // packed half2 along k
    __shared__ __align__(16) unsigned h1u[128];
    __shared__ __align__(16) unsigned h2u[128];
    __shared__ __align__(16) unsigned zu[32];
    __shared__ __align__(16) unsigned d1u[256];
    __shared__ __align__(16) unsigned d2u[256];
    __shared__ float mulv[128];
    __shared__ float pts[40];
    __shared__ float wa[4];                       // hw0, hw1, alpha0, alpha1
    __shared__ __align__(16) float red[4352];     // max: heads 64*68
    __shared__ float2 cur[192];

    if (tid < 400) {
        int k0 = 2 * tid;
        float x0 = (k0     < 784) ? x[b * 784 + k0] : 0.f;
        float x1 = (k0 + 1 < 784) ? x[b * 784 + k0 + 1] : 0.f;
        xs[tid] = pkh(x0, x1);
    }
    __syncthreads();

    // encoder L1: K=800(pad), N=256
    hgemm<256, 64, 16, 25>(wsq + Q_W1, xs, red, tid);
    __syncthreads();
    reduce_pack<256, 16, 1>(red, e_b1, h1u, tid);
    __syncthreads();

    // encoder L2: K=256, N=256
    hgemm<256, 64, 16, 8>(wsq + Q_W2, h1u, red, tid);
    __syncthreads();
    reduce_pack<256, 16, 1>(red, e_b2, h2u, tid);
    __syncthreads();

    // mu|logvar: K=256, N=128 (pairs never straddle the mu/lv split at 64)
    hgemm<128, 32, 32, 4>(wsq + Q_ML, h2u, red, tid);
    __syncthreads();
    if (tid < 64) {
        int u0 = 2 * tid;
        float s0 = (u0 < 64) ? b_mu[u0] : b_lv[u0 - 64];
        float s1 = (u0 < 64) ? b_mu[u0 + 1] : b_lv[u0 + 1 - 64];
        #pragma unroll
        for (int si = 0; si < 32; ++si) {
            s0 += red[si * 132 + u0];
            s1 += red[si * 132 + u0 + 1];
        }
        mulv[u0] = s0; mulv[u0 + 1] = s1;
        int base = (u0 < 64) ? MU_OFF : LV_OFF;
        out[base + b * 64 + (u0 & 63)]     = s0;
        out[base + b * 64 + (u0 & 63) + 1] = s1;
    }
    __syncthreads();
    if (tid < 32) {
        int j0 = 2 * tid;
        float z0 = fmaf(eps[b * 64 + j0],     expf(0.5f * mulv[64 + j0]),     mulv[j0]);
        float z1 = fmaf(eps[b * 64 + j0 + 1], expf(0.5f * mulv[64 + j0 + 1]), mulv[j0 + 1]);
        zu[tid] = pkh(z0, z1);
    }
    __syncthreads();

    // decoder L1: K=64, N=512
    hgemm<512, 128, 8, 4>(wsq + Q_D1, zu, red, tid);
    __syncthreads();
    reduce_pack<512, 8, 2>(red, d_b1, d1u, tid);
    __syncthreads();

    // decoder L2: K=512, N=512
    hgemm<512, 128, 8, 32>(wsq + Q_D2, d1u, red, tid);
    __syncthreads();
    reduce_pack<512, 8, 2>(red, d_b2, d2u, tid);
    __syncthreads();

    // heads: K=512, N=64 (44 live)
    hgemm<64, 16, 64, 4>(wsq + Q_H, d2u, red, tid);
    __syncthreads();
    if (tid < 44) {
        float s = 0.f;
        #pragma unroll
        for (int si = 0; si < 64; ++si) s += red[si * 68 + tid];
        if (tid < 40) {
            pts[tid] = tanhf(s + p_b[tid]) * 12.f + 14.f;   // CANVAS/2-MARGIN
        } else if (tid < 42) {
            float wd = sigmoidf(s + wd_b[tid - 40]) * 2.f + 1.f;
            out[W_OFF + b * 2 + (tid - 40)] = wd;
            wa[tid - 40] = 0.5f * wd;
        } else {
            float al = sigmoidf(s + a_b[tid - 42]);
            out[A_OFF + b * 2 + (tid - 42)] = al;
            wa[tid - 42 + 2] = al;
        }
    }
    __syncthreads();

    // scatter cp [P=2,S=3,4,2] from pts [P=2,PPP=10,2]; curve samples -> LDS
    if (tid < 48) {
        int p = tid / 24, rem = tid % 24;
        int s = rem / 8, kc = rem % 8;
        int k = kc >> 1, c = kc & 1;
        out[CP_OFF + b * 48 + tid] = pts[p * 20 + (3 * s + k) * 2 + c];
    }
    if (tid >= 64 && tid < 256) {
        int i = tid - 64;
        int p = i / 96, m = i % 96;
        int s = m / 32, t = m % 32;
        float u  = (t + 0.5f) * (1.f / 32.f);
        float v  = 1.f - u;
        float b0 = v * v * v;
        float b1 = 3.f * u * v * v;
        float b2 = 3.f * u * u * v;
        float b3 = u * u * u;
        const float* q = pts + p * 20 + 3 * s * 2;   // pts[p][3s..3s+3][2]
        float cx = b0 * q[0] + b1 * q[2] + b2 * q[4] + b3 * q[6];
        float cy = b0 * q[1] + b1 * q[3] + b2 * q[5] + b3 * q[7];
        cur[i] = make_float2(cx, cy);
    }
    __syncthreads();

    // ---- render tail: one pixel per thread (tid < 784) ----
    if (tid < 784) {
        int Y = tid / 28, X = tid - Y * 28;
        float px0 = X + 0.25f;
        float py0 = Y + 0.25f;

        float mA[4] = {1e30f, 1e30f, 1e30f, 1e30f};
        float mB[4] = {1e30f, 1e30f, 1e30f, 1e30f};
        #pragma unroll 4
        for (int m = 0; m < 96; ++m) {
            float2 c = cur[m];
            float dx0 = px0 - c.x, dy0 = py0 - c.y;
            float dx1 = dx0 + 0.5f, dy1 = dy0 + 0.5f;
            float xx0 = dx0 * dx0, xx1 = dx1 * dx1;
            float yy0 = dy0 * dy0, yy1 = dy1 * dy1;
            mA[0] = fminf(mA[0], xx0 + yy0);
            mA[1] = fminf(mA[1], xx1 + yy0);
            mA[2] = fminf(mA[2], xx0 + yy1);
            mA[3] = fminf(mA[3], xx1 + yy1);
        }
        #pragma unroll 4
        for (int m = 96; m < 192; ++m) {
            float2 c = cur[m];
            float dx0 = px0 - c.x, dy0 = py0 - c.y;
            float dx1 = dx0 + 0.5f, dy1 = dy0 + 0.5f;
            float xx0 = dx0 * dx0, xx1 = dx1 * dx1;
            float yy0 = dy0 * dy0, yy1 = dy1 * dy1;
            mB[0] = fminf(mB[0], xx0 + yy0);
            mB[1] = fminf(mB[1], xx1 + yy0);
            mB[2] = fminf(mB[2], xx0 + yy1);
            mB[3] = fminf(mB[3], xx1 + yy1);
        }

        const float w0 = wa[0], w1 = wa[1], al0 = wa[2], al1 = wa[3];
        float v = 0.f;
        #pragma unroll
        for (int s = 0; s < 4; ++s) {
            float d0 = sqrtf(mA[s] + 1e-12f);
            float d1 = sqrtf(mB[s] + 1e-12f);
            // cov = sigmoid((w*0.5 - d)/0.5) = sigmoid(2*(hw - d))
            float c0 = al0 / (1.f + expf(-2.f * (w0 - d0)));
            float c1 = al1 / (1.f + expf(-2.f * (w1 - d1)));
            v += (1.f - c0) * (1.f - c1);
        }
        out[REND_OFF + b * 784 + Y * 28 + X] = 1.f - 0.25f * v;
    }
}

extern "C" void kernel_launch(void* const* d_in, const int* in_sizes, int n_in,
                              void* d_out, int out_size, void* d_ws, size_t ws_size,
                              hipStream_t stream) {
    const float* x    = (const float*)d_in[0];
    const float* eps  = (const float*)d_in[1];
    const float* e_w1 = (const float*)d_in[2];
    const float* e_b1 = (const float*)d_in[3];
    const float* e_w2 = (const float*)d_in[4];
    const float* e_b2 = (const float*)d_in[5];
    const float* w_mu = (const float*)d_in[6];
    const float* b_mu = (const float*)d_in[7];
    const float* w_lv = (const float*)d_in[8];
    const float* b_lv = (const float*)d_in[9];
    const float* d_w1 = (const float*)d_in[10];
    const float* d_b1 = (const float*)d_in[11];
    const float* d_w2 = (const float*)d_in[12];
    const float* d_b2 = (const float*)d_in[13];
    const float* p_w  = (const float*)d_in[14];
    const float* p_b  = (const float*)d_in[15];
    const float* wd_w = (const float*)d_in[16];
    const float* wd_b = (const float*)d_in[17];
    const float* a_w  = (const float*)d_in[18];
    const float* a_b  = (const float*)d_in[19];
    float* out = (float*)d_out;
    uint4* wsq = (uint4*)d_ws;

    hipLaunchKernelGGL(conv_w, dim3((Q_TOT + 255) / 256), dim3(256), 0, stream,
                       e_w1, e_w2, w_mu, w_lv, d_w1, d_w2, p_w, wd_w, a_w, wsq);
    hipLaunchKernelGGL(vae_mlp, dim3(128), dim3(1024), 0, stream,
                       x, eps, e_b1, e_b2, b_mu, b_lv, d_b1, d_b2,
                       p_b, wd_b, a_b, wsq, out);
}

// Round 11
// 124.634 us; speedup vs baseline: 1.0407x; 1.0407x over previous
//
#include <hip/hip_runtime.h>
#include <hip/hip_bf16.h>
#include <hip/hip_fp16.h>
#include <math.h>

// Output layout (float32, concatenated in reference return order):
//   rendered [128,1,28,28]  @ 0       (100352)
//   mu       [128,64]       @ 100352  (8192)
//   logvar   [128,64]       @ 108544  (8192)
//   cp       [128,2,3,4,2]  @ 116736  (6144)
//   widths   [128,2]        @ 122880  (256)
//   alphas   [128,2]        @ 123136  (256)
#define REND_OFF 0
#define MU_OFF   100352
#define LV_OFF   108544
#define CP_OFF   116736
#define W_OFF    122880
#define A_OFF    123136

// fp16 weight workspace, k-pair COLUMN packed for v_dot2_f32_f16:
// uint4 q at (k2, j4): q.x = {W[2k2][4j4], W[2k2+1][4j4]} as half2, q.y..q.w
// the next 3 columns. Layer uint4 bases:
#define Q_W1 0       // [400][64]  (K padded 784->800)
#define Q_W2 25600   // [128][64]
#define Q_ML 33792   // [128][32]  (mu|lv fused, N=128)
#define Q_D1 37888   // [32][128]
#define Q_D2 41984   // [256][128]
#define Q_H  74752   // [256][16]  (p|wd|a|pad0, N=64)
#define Q_TOT 78848

typedef _Float16 half2_t __attribute__((ext_vector_type(2)));

__device__ __forceinline__ float leakyf(float x) {
    return x >= 0.f ? x : 0.2f * x;
}
__device__ __forceinline__ float seluf(float x) {
    const float sc = 1.0507009873554805f;
    const float al = 1.6732632423543772f;
    return x > 0.f ? sc * x : sc * al * expm1f(x);
}
__device__ __forceinline__ float sigmoidf(float x) {
    return 1.f / (1.f + expf(-x));
}
__device__ __forceinline__ unsigned pkh(float a, float b) {
    __half ha = __float2half(a), hb = __float2half(b);
    return (unsigned)__half_as_ushort(ha) | ((unsigned)__half_as_ushort(hb) << 16);
}
__device__ __forceinline__ half2_t as_h2(unsigned u) {
    union { unsigned u; half2_t h; } c; c.u = u; return c.h;
}
__device__ __forceinline__ float dot2(unsigned a, unsigned w, float acc) {
#if __has_builtin(__builtin_amdgcn_fdot2)
    return __builtin_amdgcn_fdot2(as_h2(a), as_h2(w), acc, false);
#else
    half2_t ah = as_h2(a), wh = as_h2(w);
    acc = fmaf((float)ah[0], (float)wh[0], acc);
    return fmaf((float)ah[1], (float)wh[1], acc);
#endif
}

// ---- kernel 0: build k-pair column-packed fp16 weight workspace ----
__global__ __launch_bounds__(256) void conv_w(
    const float* __restrict__ e_w1, const float* __restrict__ e_w2,
    const float* __restrict__ w_mu, const float* __restrict__ w_lv,
    const float* __restrict__ d_w1, const float* __restrict__ d_w2,
    const float* __restrict__ p_w,  const float* __restrict__ wd_w,
    const float* __restrict__ a_w,  uint4* __restrict__ wsq)
{
    int t = blockIdx.x * 256 + threadIdx.x;
    if (t >= Q_TOT) return;
    float lo[4], hi[4];
    if (t < Q_W2) {                       // W1: [800pad][256]
        int q = t, k2 = q >> 6, j4 = q & 63;
        int k0 = 2 * k2, c0 = 4 * j4;
        #pragma unroll
        for (int c = 0; c < 4; ++c) {
            lo[c] = (k0     < 784) ? e_w1[k0 * 256 + c0 + c] : 0.f;
            hi[c] = (k0 + 1 < 784) ? e_w1[(k0 + 1) * 256 + c0 + c] : 0.f;
        }
    } else if (t < Q_ML) {                // W2: [256][256]
        int q = t - Q_W2, k2 = q >> 6, j4 = q & 63;
        int k0 = 2 * k2, c0 = 4 * j4;
        #pragma unroll
        for (int c = 0; c < 4; ++c) {
            lo[c] = e_w2[k0 * 256 + c0 + c];
            hi[c] = e_w2[(k0 + 1) * 256 + c0 + c];
        }
    } else if (t < Q_D1) {                // ML: [256][128] = mu|lv
        int q = t - Q_ML, k2 = q >> 5, j4 = q & 31;
        int k0 = 2 * k2, c0 = 4 * j4;
        #pragma unroll
        for (int c = 0; c < 4; ++c) {
            int cc = c0 + c;
            lo[c] = (cc < 64) ? w_mu[k0 * 64 + cc] : w_lv[k0 * 64 + cc - 64];
            hi[c] = (cc < 64) ? w_mu[(k0 + 1) * 64 + cc]
                              : w_lv[(k0 + 1) * 64 + cc - 64];
        }
    } else if (t < Q_D2) {                // D1: [64][512]
        int q = t - Q_D1, k2 = q >> 7, j4 = q & 127;
        int k0 = 2 * k2, c0 = 4 * j4;
        #pragma unroll
        for (int c = 0; c < 4; ++c) {
            lo[c] = d_w1[k0 * 512 + c0 + c];
            hi[c] = d_w1[(k0 + 1) * 512 + c0 + c];
        }
    } else if (t < Q_H) {                 // D2: [512][512]
        int q = t - Q_D2, k2 = q >> 7, j4 = q & 127;
        int k0 = 2 * k2, c0 = 4 * j4;
        #pragma unroll
        for (int c = 0; c < 4; ++c) {
            lo[c] = d_w2[k0 * 512 + c0 + c];
            hi[c] = d_w2[(k0 + 1) * 512 + c0 + c];
        }
    } else {                              // H: [512][64] = p|wd|a|0
        int q = t - Q_H, k2 = q >> 4, j4 = q & 15;
        int k0 = 2 * k2, c0 = 4 * j4;
        #pragma unroll
        for (int c = 0; c < 4; ++c) {
            int cc = c0 + c;
            lo[c] = (cc < 40) ? p_w[k0 * 40 + cc]
                  : (cc < 42) ? wd_w[k0 * 2 + cc - 40]
                  : (cc < 44) ? a_w[k0 * 2 + cc - 42] : 0.f;
            hi[c] = (cc < 40) ? p_w[(k0 + 1) * 40 + cc]
                  : (cc < 42) ? wd_w[(k0 + 1) * 2 + cc - 40]
                  : (cc < 44) ? a_w[(k0 + 1) * 2 + cc - 42] : 0.f;
        }
    }
    uint4 u;
    u.x = pkh(lo[0], hi[0]);
    u.y = pkh(lo[1], hi[1]);
    u.z = pkh(lo[2], hi[2]);
    u.w = pkh(lo[3], hi[3]);
    wsq[t] = u;
}

// ---- layer slice GEMM via v_dot2_f32_f16: 16B weight loads, b32 act ----
// N cols, JG = N/4 col groups, S = 1024/JG k-slices, Ks k-pairs per thread.
template<int N, int JG, int S, int Ks>
__device__ __forceinline__ void hgemm(const uint4* __restrict__ wq,
                                      const unsigned* __restrict__ xu,
                                      float* __restrict__ red, int tid)
{
    constexpr int NTp = N + 4;
    const int jg = tid % JG, ks = tid / JG;
    const uint4* wp = wq + (ks * Ks) * (N / 4) + jg;
    const unsigned* xp = xu + ks * Ks;
    float a0 = 0.f, a1 = 0.f, a2 = 0.f, a3 = 0.f;
    #pragma unroll 8
    for (int kk = 0; kk < Ks; ++kk) {
        uint4 w = wp[kk * (N / 4)];
        unsigned av = xp[kk];
        a0 = dot2(av, w.x, a0);
        a1 = dot2(av, w.y, a1);
        a2 = dot2(av, w.z, a2);
        a3 = dot2(av, w.w, a3);
    }
    *(float4*)&red[ks * NTp + 4 * jg] = make_float4(a0, a1, a2, a3);
}

// reduce S slices, apply act, pack adjacent unit pairs to half2
template<int N, int S, int ACT>
__device__ __forceinline__ void reduce_pack(const float* __restrict__ red,
                                            const float* __restrict__ bias,
                                            unsigned* __restrict__ Cu, int tid)
{
    constexpr int NTp = N + 4;
    if (tid < N / 2) {
        int j0 = 2 * tid;
        float s0 = bias[j0], s1 = bias[j0 + 1];
        #pragma unroll
        for (int si = 0; si < S; ++si) {
            s0 += red[si * NTp + j0];
            s1 += red[si * NTp + j0 + 1];
        }
        if (ACT == 1) { s0 = leakyf(s0); s1 = leakyf(s1); }
        else          { s0 = seluf(s0);  s1 = seluf(s1);  }
        Cu[tid] = pkh(s0, s1);
    }
}

// ---- fused MLP: 128 blocks x 1024 thr; 1 batch elem per block ----
__global__ __launch_bounds__(1024) void vae_mlp(
    const float* __restrict__ x,    const float* __restrict__ eps,
    const float* __restrict__ e_b1, const float* __restrict__ e_b2,
    const float* __restrict__ b_mu, const float* __restrict__ b_lv,
    const float* __restrict__ d_b1, const float* __restrict__ d_b2,
    const float* __restrict__ p_b,  const float* __restrict__ wd_b,
    const float* __restrict__ a_b,
    const uint4* __restrict__ wsq,  float* __restrict__ out)
{
    const int b   = blockIdx.x;
    const int tid = threadIdx.x;

    __shared__ __align__(16) unsigned xs[400];    // packed half2 along k
    __shared__ __align__(16) unsigned h1u[128];
    __shared__ __align__(16) unsigned h2u[128];
    __shared__ __align__(16) unsigned zu[32];
    __shared__ __align__(16) unsigned d1u[256];
    __shared__ __align__(16) unsigned d2u[256];
    __shared__ float mulv[128];
    __shared__ float pts[40];
    __shared__ __align__(16) float red[4352];     // max: heads 64*68

    if (tid < 400) {
        int k0 = 2 * tid;
        float x0 = (k0     < 784) ? x[b * 784 + k0] : 0.f;
        float x1 = (k0 + 1 < 784) ? x[b * 784 + k0 + 1] : 0.f;
        xs[tid] = pkh(x0, x1);
    }
    __syncthreads();

    // encoder L1: K=800(pad), N=256
    hgemm<256, 64, 16, 25>(wsq + Q_W1, xs, red, tid);
    __syncthreads();
    reduce_pack<256, 16, 1>(red, e_b1, h1u, tid);
    __syncthreads();

    // encoder L2: K=256, N=256
    hgemm<256, 64, 16, 8>(wsq + Q_W2, h1u, red, tid);
    __syncthreads();
    reduce_pack<256, 16, 1>(red, e_b2, h2u, tid);
    __syncthreads();

    // mu|logvar: K=256, N=128 (pairs never straddle the mu/lv split at 64)
    hgemm<128, 32, 32, 4>(wsq + Q_ML, h2u, red, tid);
    __syncthreads();
    if (tid < 64) {
        int u0 = 2 * tid;
        float s0 = (u0 < 64) ? b_mu[u0] : b_lv[u0 - 64];
        float s1 = (u0 < 64) ? b_mu[u0 + 1] : b_lv[u0 + 1 - 64];
        #pragma unroll
        for (int si = 0; si < 32; ++si) {
            s0 += red[si * 132 + u0];
            s1 += red[si * 132 + u0 + 1];
        }
        mulv[u0] = s0; mulv[u0 + 1] = s1;
        int base = (u0 < 64) ? MU_OFF : LV_OFF;
        out[base + b * 64 + (u0 & 63)]     = s0;
        out[base + b * 64 + (u0 & 63) + 1] = s1;
    }
    __syncthreads();
    if (tid < 32) {
        int j0 = 2 * tid;
        float z0 = fmaf(eps[b * 64 + j0],     expf(0.5f * mulv[64 + j0]),     mulv[j0]);
        float z1 = fmaf(eps[b * 64 + j0 + 1], expf(0.5f * mulv[64 + j0 + 1]), mulv[j0 + 1]);
        zu[tid] = pkh(z0, z1);
    }
    __syncthreads();

    // decoder L1: K=64, N=512
    hgemm<512, 128, 8, 4>(wsq + Q_D1, zu, red, tid);
    __syncthreads();
    reduce_pack<512, 8, 2>(red, d_b1, d1u, tid);
    __syncthreads();

    // decoder L2: K=512, N=512
    hgemm<512, 128, 8, 32>(wsq + Q_D2, d1u, red, tid);
    __syncthreads();
    reduce_pack<512, 8, 2>(red, d_b2, d2u, tid);
    __syncthreads();

    // heads: K=512, N=64 (44 live)
    hgemm<64, 16, 64, 4>(wsq + Q_H, d2u, red, tid);
    __syncthreads();
    if (tid < 44) {
        float s = 0.f;
        #pragma unroll
        for (int si = 0; si < 64; ++si) s += red[si * 68 + tid];
        if (tid < 40) {
            pts[tid] = tanhf(s + p_b[tid]) * 12.f + 14.f;   // CANVAS/2-MARGIN
        } else if (tid < 42) {
            out[W_OFF + b * 2 + (tid - 40)] =
                sigmoidf(s + wd_b[tid - 40]) * 2.f + 1.f;
        } else {
            out[A_OFF + b * 2 + (tid - 42)] = sigmoidf(s + a_b[tid - 42]);
        }
    }
    __syncthreads();

    // scatter cp [P=2,S=3,4,2] from pts [P=2,PPP=10,2]
    if (tid < 48) {
        int p = tid / 24, rem = tid % 24;
        int s = rem / 8, kc = rem % 8;
        int k = kc >> 1, c = kc & 1;
        out[CP_OFF + b * 48 + tid] = pts[p * 20 + (3 * s + k) * 2 + c];
    }
}

// ---- render: grid (128, 4), 256 threads; block (b,q) -> pixel rows 7q.. ----
__global__ __launch_bounds__(256) void vae_render(float* __restrict__ out)
{
    const int b   = blockIdx.x;
    const int q   = blockIdx.y;
    const int tid = threadIdx.x;

    __shared__ float2 cur[192];
    __shared__ float  wa[4];

    if (tid < 192) {
        int p = tid / 96;
        int m = tid % 96;
        int s = m / 32;
        int t = m % 32;
        float u  = (t + 0.5f) * (1.f / 32.f);
        float v  = 1.f - u;
        float b0 = v * v * v;
        float b1 = 3.f * u * v * v;
        float b2 = 3.f * u * u * v;
        float b3 = u * u * u;
        const float* cp = out + CP_OFF + b * 48 + p * 24 + s * 8;
        float cx = b0 * cp[0] + b1 * cp[2] + b2 * cp[4] + b3 * cp[6];
        float cy = b0 * cp[1] + b1 * cp[3] + b2 * cp[5] + b3 * cp[7];
        cur[tid] = make_float2(cx, cy);
    } else if (tid < 196) {
        int i = tid - 192;
        wa[i] = (i < 2) ? 0.5f * out[W_OFF + b * 2 + i]
                        : out[A_OFF + b * 2 + (i - 2)];
    }
    __syncthreads();

    if (tid < 196) {
        int Y = tid / 28, X = tid - Y * 28;
        float px0 = X + 0.25f;
        float py0 = (7 * q + Y) + 0.25f;

        float mA[4] = {1e30f, 1e30f, 1e30f, 1e30f};
        float mB[4] = {1e30f, 1e30f, 1e30f, 1e30f};
        #pragma unroll 4
        for (int m = 0; m < 96; ++m) {
            float2 c = cur[m];
            float dx0 = px0 - c.x, dy0 = py0 - c.y;
            float dx1 = dx0 + 0.5f, dy1 = dy0 + 0.5f;
            float xx0 = dx0 * dx0, xx1 = dx1 * dx1;
            float yy0 = dy0 * dy0, yy1 = dy1 * dy1;
            mA[0] = fminf(mA[0], xx0 + yy0);
            mA[1] = fminf(mA[1], xx1 + yy0);
            mA[2] = fminf(mA[2], xx0 + yy1);
            mA[3] = fminf(mA[3], xx1 + yy1);
        }
        #pragma unroll 4
        for (int m = 96; m < 192; ++m) {
            float2 c = cur[m];
            float dx0 = px0 - c.x, dy0 = py0 - c.y;
            float dx1 = dx0 + 0.5f, dy1 = dy0 + 0.5f;
            float xx0 = dx0 * dx0, xx1 = dx1 * dx1;
            float yy0 = dy0 * dy0, yy1 = dy1 * dy1;
            mB[0] = fminf(mB[0], xx0 + yy0);
            mB[1] = fminf(mB[1], xx1 + yy0);
            mB[2] = fminf(mB[2], xx0 + yy1);
            mB[3] = fminf(mB[3], xx1 + yy1);
        }

        const float w0 = wa[0], w1 = wa[1], a0 = wa[2], a1 = wa[3];
        float v = 0.f;
        #pragma unroll
        for (int s = 0; s < 4; ++s) {
            float d0 = sqrtf(mA[s] + 1e-12f);
            float d1 = sqrtf(mB[s] + 1e-12f);
            float c0 = a0 / (1.f + expf(-2.f * (w0 - d0)));
            float c1 = a1 / (1.f + expf(-2.f * (w1 - d1)));
            v += (1.f - c0) * (1.f - c1);
        }
        out[REND_OFF + b * 784 + (7 * q + Y) * 28 + X] = 1.f - 0.25f * v;
    }
}

extern "C" void kernel_launch(void* const* d_in, const int* in_sizes, int n_in,
                              void* d_out, int out_size, void* d_ws, size_t ws_size,
                              hipStream_t stream) {
    const float* x    = (const float*)d_in[0];
    const float* eps  = (const float*)d_in[1];
    const float* e_w1 = (const float*)d_in[2];
    const float* e_b1 = (const float*)d_in[3];
    const float* e_w2 = (const float*)d_in[4];
    const float* e_b2 = (const float*)d_in[5];
    const float* w_mu = (const float*)d_in[6];
    const float* b_mu = (const float*)d_in[7];
    const float* w_lv = (const float*)d_in[8];
    const float* b_lv = (const float*)d_in[9];
    const float* d_w1 = (const float*)d_in[10];
    const float* d_b1 = (const float*)d_in[11];
    const float* d_w2 = (const float*)d_in[12];
    const float* d_b2 = (const float*)d_in[13];
    const float* p_w  = (const float*)d_in[14];
    const float* p_b  = (const float*)d_in[15];
    const float* wd_w = (const float*)d_in[16];
    const float* wd_b = (const float*)d_in[17];
    const float* a_w  = (const float*)d_in[18];
    const float* a_b  = (const float*)d_in[19];
    float* out = (float*)d_out;
    uint4* wsq = (uint4*)d_ws;

    hipLaunchKernelGGL(conv_w, dim3((Q_TOT + 255) / 256), dim3(256), 0, stream,
                       e_w1, e_w2, w_mu, w_lv, d_w1, d_w2, p_w, wd_w, a_w, wsq);
    hipLaunchKernelGGL(vae_mlp, dim3(128), dim3(1024), 0, stream,
                       x, eps, e_b1, e_b2, b_mu, b_lv, d_b1, d_b2,
                       p_b, wd_b, a_b, wsq, out);
    hipLaunchKernelGGL(vae_render, dim3(128, 4), dim3(256), 0, stream, out);
}